// Round 9
// baseline (95.452 us; speedup 1.0000x reference)
//
#include <hip/hip_runtime.h>
#include <math.h>
#include <stdint.h>

// H[r,t] = (1/128) * sum_l alpha_l * exp(j*pi*r*sin(theta_r_l)) * exp(-j*pi*t*sin(theta_t_l))
// Output: out_size == 1024*1024 -> Re(H).
// Re(H) = A * B^T with K interleaved as (re,im) pairs per ray:
//   A[r][2l]   = C*(ar*cos(phi) - ai*sin(phi)),  phi = pi*r*sin(theta_r_l), C = 1/128
//   A[r][2l+1] = C*(ar*sin(phi) + ai*cos(phi))
//   B[t][2l]   = cos(psi),  psi = pi*t*sin(theta_t_l)
//   B[t][2l+1] = sin(psi)
// r9: BARRIER-FREE K-loop. Both MFMA operands generated directly in registers
// (gen slot layout == MFMA fragment layout, r6/r8-validated): each wave makes
// its own A-frags (rows wr*64.., chained +16 via dA=e^{j*2pi*8*sr}) and
// B-frags (cols wc*64.., chained +16 via dB=e^{j*2pi*8*st}). No As/Bs LDS, no
// __syncthreads in the loop -> gen VALU/trans co-issues with MFMA across
// drifting waves. sP/sD are read-only LDS broadcast tables (one barrier).
// fp32 split-K partials (SPLITK=8), reduced by a second kernel.

#define N_T 1024
#define N_R 1024
#define L_RAYS 8192

#define BM 128
#define BN 128
#define NTILES 64           // 8x8 tile grid
#define SPLITK 8
#define RAYS_PER_BLK 1024   // L_RAYS / SPLITK
#define KSTEPS 64           // 16 rays (32 K) per step

typedef __attribute__((ext_vector_type(8))) short bf16x8;
typedef __attribute__((ext_vector_type(4))) float f32x4;
typedef __attribute__((ext_vector_type(4))) unsigned int u32x4;

static __device__ __forceinline__ unsigned pk_bf16(float lo, float hi) {
    unsigned o;
    asm("v_cvt_pk_bf16_f32 %0, %1, %2" : "=v"(o) : "v"(lo), "v"(hi));
    return o;
}

// ------------------------------------------------------------- fused GEMM
// grid = 64 tiles * SPLITK(8) = 512 blocks (2/CU), 256 threads (4 waves, 2x2).
// Fragment register layout (validated r5/r6/r8): lane holds row/col
// (frag*16 + (lane&15)), rays (lane>>4)*4 .. +3, (re,im) packed per u32.
__global__ __launch_bounds__(256, 3) void fused_gemm_kernel(
    const float* __restrict__ alpha_re, const float* __restrict__ alpha_im,
    const float* __restrict__ theta_t, const float* __restrict__ theta_r,
    float* __restrict__ Pout)  // [SPLITK][N_R][N_T] fp32 partials
{
    __shared__ float4 sP[RAYS_PER_BLK];   // 16 KB: (0.5*sin_r, 0.5*sin_t, ar*C, ai*C)
    __shared__ float4 sD[RAYS_PER_BLK];   // 16 KB: (dA16.re, dA16.im, dB16.re, dB16.im)

    const int tid  = threadIdx.x;
    const int wave = tid >> 6;          // 0..3
    const int lane = tid & 63;
    const int bid  = blockIdx.x;
    const int tile = bid & (NTILES - 1);
    const int sk   = bid >> 6;          // split-K slice 0..7
    const int r0 = (tile >> 3) * BM;
    const int c0 = (tile & 7) * BN;

    // per-ray parameters + +16-row/col chain deltas for this K-slice.
    // phase slope per row/col: 0.5*sin (revolutions); +16 step -> 8*sin rev.
    for (int i = tid; i < RAYS_PER_BLK; i += 256) {
        const int l = sk * RAYS_PER_BLK + i;
        const float C = 0.0078125f;     // 1/128
        const float sr = sinf(theta_r[l]);
        const float st = sinf(theta_t[l]);
        sP[i] = make_float4(0.5f * sr, 0.5f * st, alpha_re[l] * C, alpha_im[l] * C);
        float uA = 8.0f * sr;  uA -= rintf(uA);
        float uB = 8.0f * st;  uB -= rintf(uB);
        sD[i] = make_float4(__builtin_amdgcn_cosf(uA), __builtin_amdgcn_sinf(uA),
                            __builtin_amdgcn_cosf(uB), __builtin_amdgcn_sinf(uB));
    }
    __syncthreads();   // the ONLY barrier: sP/sD tables ready

    f32x4 acc[4][4];
    #pragma unroll
    for (int m = 0; m < 4; ++m)
        #pragma unroll
        for (int n = 0; n < 4; ++n)
            acc[m][n] = (f32x4){0.f, 0.f, 0.f, 0.f};

    const int k8   = lane >> 4;         // ray sub-group 0..3
    const int rsub = lane & 15;         // row/col within fragment
    const int wr = wave >> 1;           // 0..1: row half (64 rows)
    const int wc = wave & 1;            // 0..1: col half (64 cols)

    // this wave's own operand rows/cols (consume set == gen set)
    const float rwA = (float)(r0 + wr * 64 + rsub);
    const float twB = (float)(c0 + wc * 64 + rsub);

    for (int kt = 0; kt < KSTEPS; ++kt) {
        const int lidx = kt * 16 + k8 * 4;   // ray base for this k-group
        unsigned oa[4][4], ob[4][4];         // [frag q][ray j]
        #pragma unroll
        for (int j = 0; j < 4; ++j) {
            const float4 p = sP[lidx + j];
            const float4 d = sD[lidx + j];
            // --- A: base phasor * alpha at row rwA, chain +16 rows via (d.x,d.y)
            float u = rwA * p.x;  u -= rintf(u);
            const float asn = __builtin_amdgcn_sinf(u);
            const float acs = __builtin_amdgcn_cosf(u);
            float re = p.z * acs - p.w * asn;
            float im = p.z * asn + p.w * acs;
            oa[0][j] = pk_bf16(re, im);
            #pragma unroll
            for (int q = 1; q < 4; ++q) {
                const float t = re * d.x - im * d.y;
                im = re * d.y + im * d.x;
                re = t;
                oa[q][j] = pk_bf16(re, im);
            }
            // --- B: unit phasor at col twB, chain +16 cols via (d.z,d.w)
            float ub = twB * p.y;  ub -= rintf(ub);
            float bim = __builtin_amdgcn_sinf(ub);
            float bre = __builtin_amdgcn_cosf(ub);
            ob[0][j] = pk_bf16(bre, bim);
            #pragma unroll
            for (int q = 1; q < 4; ++q) {
                const float t = bre * d.z - bim * d.w;
                bim = bre * d.w + bim * d.z;
                bre = t;
                ob[q][j] = pk_bf16(bre, bim);
            }
        }
        // assemble fragments (pure register moves, static indices)
        bf16x8 a[4], b[4];
        #pragma unroll
        for (int m = 0; m < 4; ++m) {
            const u32x4 ta = (u32x4){oa[m][0], oa[m][1], oa[m][2], oa[m][3]};
            const u32x4 tb = (u32x4){ob[m][0], ob[m][1], ob[m][2], ob[m][3]};
            a[m] = __builtin_bit_cast(bf16x8, ta);
            b[m] = __builtin_bit_cast(bf16x8, tb);
        }
        __builtin_amdgcn_s_setprio(1);
        #pragma unroll
        for (int m = 0; m < 4; ++m)
            #pragma unroll
            for (int n = 0; n < 4; ++n)
                acc[m][n] = __builtin_amdgcn_mfma_f32_16x16x32_bf16(a[m], b[n], acc[m][n], 0, 0, 0);
        __builtin_amdgcn_s_setprio(0);
    }

    // C/D layout (m89/m91): col = lane&15, row = (lane>>4)*4 + reg
    float* P = Pout + (size_t)sk * (N_R * N_T);
    const int crow0 = r0 + wr * 64 + (lane >> 4) * 4;
    const int ccol0 = c0 + wc * 64 + (lane & 15);
    #pragma unroll
    for (int m = 0; m < 4; ++m)
        #pragma unroll
        for (int n = 0; n < 4; ++n)
            #pragma unroll
            for (int j = 0; j < 4; ++j)
                P[(size_t)(crow0 + m * 16 + j) * N_T + ccol0 + n * 16] = acc[m][n][j];
}

// ------------------------------------------------------------- split-K reduce
__global__ __launch_bounds__(256) void reduce_kernel(
    const f32x4* __restrict__ P, f32x4* __restrict__ out)
{
    const int i = blockIdx.x * 256 + threadIdx.x;   // over N_R*N_T/4
    const int n4 = (N_R * N_T) / 4;
    f32x4 s = P[i];
    #pragma unroll
    for (int sk = 1; sk < SPLITK; ++sk) s += P[(size_t)sk * n4 + i];
    out[i] = s;
}

// ------------------------------------------------------------- fp32 fallback
#define TILE 64
#define KC 32
__global__ __launch_bounds__(256) void geo_channel_fallback(
    const float* __restrict__ alpha_re, const float* __restrict__ alpha_im,
    const float* __restrict__ theta_t, const float* __restrict__ theta_r,
    float* __restrict__ out, int interleaved)
{
    __shared__ float sAr[KC][TILE][2];
    __shared__ float sAt[KC][TILE][2];
    const int tid = threadIdx.x;
    const int bid = blockIdx.x;
    const int r0 = (bid / (N_T / TILE)) * TILE;
    const int t0 = (bid % (N_T / TILE)) * TILE;
    const int tx = tid & 15;
    const int ty = tid >> 4;
    float accRe[4][4] = {{0.f}};
    float accIm[4][4] = {{0.f}};
    const float C = 1.0f / 128.0f;
    const float PI = 3.14159265358979323846f;
    for (int lc = 0; lc < L_RAYS; lc += KC) {
        __syncthreads();
        for (int idx = tid; idx < KC * TILE; idx += 256) {
            const int ll = idx >> 6;
            const int rr = idx & 63;
            const int l = lc + ll;
            const float are = alpha_re[l] * C;
            const float aim = alpha_im[l] * C;
            const float srr = sinf(theta_r[l]);
            const float stt = sinf(theta_t[l]);
            {
                float x = (float)(r0 + rr) * srr;
                float f = x - 2.0f * rintf(0.5f * x);
                float s, c;
                __sincosf(PI * f, &s, &c);
                sAr[ll][rr][0] = are * c - aim * s;
                sAr[ll][rr][1] = are * s + aim * c;
            }
            {
                float x = (float)(t0 + rr) * stt;
                float f = x - 2.0f * rintf(0.5f * x);
                float s, c;
                __sincosf(PI * f, &s, &c);
                sAt[ll][rr][0] = c;
                sAt[ll][rr][1] = s;
            }
        }
        __syncthreads();
        #pragma unroll 4
        for (int ll = 0; ll < KC; ++ll) {
            const float4 arv0 = *reinterpret_cast<const float4*>(&sAr[ll][ty * 4 + 0][0]);
            const float4 arv1 = *reinterpret_cast<const float4*>(&sAr[ll][ty * 4 + 2][0]);
            const float4 atv0 = *reinterpret_cast<const float4*>(&sAt[ll][tx * 4 + 0][0]);
            const float4 atv1 = *reinterpret_cast<const float4*>(&sAt[ll][tx * 4 + 2][0]);
            const float arre[4] = {arv0.x, arv0.z, arv1.x, arv1.z};
            const float arim[4] = {arv0.y, arv0.w, arv1.y, arv1.w};
            const float atre[4] = {atv0.x, atv0.z, atv1.x, atv1.z};
            const float atim[4] = {atv0.y, atv0.w, atv1.y, atv1.w};
            #pragma unroll
            for (int i = 0; i < 4; ++i)
                #pragma unroll
                for (int j = 0; j < 4; ++j) {
                    accRe[i][j] = fmaf(arre[i], atre[j], fmaf(arim[i], atim[j], accRe[i][j]));
                    accIm[i][j] = fmaf(arim[i], atre[j], fmaf(-arre[i], atim[j], accIm[i][j]));
                }
        }
    }
    #pragma unroll
    for (int i = 0; i < 4; ++i) {
        const int r = r0 + ty * 4 + i;
        #pragma unroll
        for (int j = 0; j < 4; ++j) {
            const int t = t0 + tx * 4 + j;
            if (interleaved) {
                out[2 * (r * N_T + t) + 0] = accRe[i][j];
                out[2 * (r * N_T + t) + 1] = accIm[i][j];
            } else {
                out[r * N_T + t] = accRe[i][j];
            }
        }
    }
}

// ------------------------------------------------------------- launch
extern "C" void kernel_launch(void* const* d_in, const int* in_sizes, int n_in,
                              void* d_out, int out_size, void* d_ws, size_t ws_size,
                              hipStream_t stream) {
    const float* alpha_re = (const float*)d_in[0];
    const float* alpha_im = (const float*)d_in[1];
    const float* theta_t  = (const float*)d_in[2];
    const float* theta_r  = (const float*)d_in[3];
    float* out = (float*)d_out;

    const int interleaved = (out_size >= 2 * N_R * N_T) ? 1 : 0;
    const size_t needP = (size_t)SPLITK * N_R * N_T * 4;   // 32 MB fp32 partials

    if (interleaved || ws_size < needP) {
        const int nblocks = (N_R / TILE) * (N_T / TILE);
        geo_channel_fallback<<<nblocks, 256, 0, stream>>>(
            alpha_re, alpha_im, theta_t, theta_r, out, interleaved);
        return;
    }

    float* P = (float*)d_ws;
    fused_gemm_kernel<<<NTILES * SPLITK, 256, 0, stream>>>(
        alpha_re, alpha_im, theta_t, theta_r, P);
    reduce_kernel<<<(N_R * N_T / 4) / 256, 256, 0, stream>>>(
        (const f32x4*)P, (f32x4*)out);
}